// Round 1
// baseline (680.415 us; speedup 1.0000x reference)
//
#include <hip/hip_runtime.h>
#include <hip/hip_bf16.h>

#define B_ROWS 262144
#define IN_DIM 65

typedef short short8 __attribute__((ext_vector_type(8)));
typedef float f32x4 __attribute__((ext_vector_type(4)));

static __device__ __forceinline__ short f2bf(float f) {
    union { float f; unsigned u; } v; v.f = f;
    unsigned r = v.u + 0x7fff + ((v.u >> 16) & 1);   // RNE
    return (short)(r >> 16);
}

// ---------------- weight conversion: fp32 -> bf16 into d_ws ----------------
// layout in ws (shorts): W1' [128][64] @0, W2' [64][128] @8192, W3' [256][64] @16384
__global__ void convert_weights(const float* __restrict__ W1,
                                const float* __restrict__ W2,
                                const float* __restrict__ W3,
                                short* __restrict__ ws) {
    int tid = blockIdx.x * 256 + threadIdx.x;
    if (tid < 8192) {
        int n = tid >> 6, k = tid & 63;
        ws[tid] = f2bf(W1[n * IN_DIM + k]);          // drop col 64 (handled in fp32)
    } else if (tid < 16384) {
        int t = tid - 8192;
        ws[tid] = f2bf(W2[t]);                       // 64x128 row-major, verbatim
    } else if (tid < 32768) {
        int t = tid - 16384;
        ws[tid] = f2bf(W3[t]);                       // 256x64 row-major, verbatim
    }
}

// ---------------- main fused kernel ----------------
// block = 256 threads = 4 independent waves; each wave does 16 rows end-to-end.
__global__ __launch_bounds__(256) void policy_kernel(
    const float* __restrict__ inp,        // (B, 65)
    const int*   __restrict__ scale_table,// (16,)
    const float* __restrict__ W1,         // (128, 65) fp32 (for col-64 fixup)
    const float* __restrict__ b1,         // (128,)
    const float* __restrict__ b2,         // (64,)
    const float* __restrict__ b3,         // (256,)
    const short* __restrict__ wbf,        // bf16 weights in ws
    float* __restrict__ out)              // probs (B,256) then mask (B,256)
{
    // per-wave LDS slices; strides 136 / 72 give 2-way (free) bank aliasing
    __shared__ __align__(16) short sH1[4][16 * 136];
    __shared__ __align__(16) short sH2[4][16 * 72];

    const int wave = threadIdx.x >> 6;
    const int lane = threadIdx.x & 63;
    const int l = lane & 15;      // col-of-tile / A-row
    const int q = lane >> 4;      // quad

    const int rb = blockIdx.x * 64 + wave * 16;   // 16-row tile base
    const int row_l = rb + l;

    const short* W1b = wbf;          // 128 x 64
    const short* W2b = wbf + 8192;   // 64 x 128
    const short* W3b = wbf + 16384;  // 256 x 64

    // ---- A1 fragments: A[m=lane&15][k=q*8+j], k in [0,64) ----
    short8 a1[2];
    {
        const float* rowp = inp + (size_t)row_l * IN_DIM;
        #pragma unroll
        for (int s = 0; s < 2; s++) {
            #pragma unroll
            for (int j = 0; j < 8; j++)
                a1[s][j] = f2bf(rowp[s * 32 + q * 8 + j]);
        }
    }

    // dim idx + scale per accumulator row (rows q*4+r in C-layout)
    float dimf[4]; int scl[4];
    #pragma unroll
    for (int r = 0; r < 4; r++) {
        dimf[r] = inp[(size_t)(rb + q * 4 + r) * IN_DIM + 64];
        scl[r]  = scale_table[(int)dimf[r]];
    }

    short* sh1 = sH1[wave];
    short* sh2 = sH2[wave];

    // ---- layer 1: 65 -> 128, relu ----
    #pragma unroll
    for (int nt = 0; nt < 8; nt++) {
        f32x4 c = {0.f, 0.f, 0.f, 0.f};
        #pragma unroll
        for (int s = 0; s < 2; s++) {
            short8 b = *(const short8*)(W1b + (nt * 16 + l) * 64 + s * 32 + q * 8);
            c = __builtin_amdgcn_mfma_f32_16x16x32_bf16(a1[s], b, c, 0, 0, 0);
        }
        const int cidx = nt * 16 + l;
        const float w64  = W1[(size_t)cidx * IN_DIM + 64];  // col-64 fixup (fp32)
        const float bias = b1[cidx];
        #pragma unroll
        for (int r = 0; r < 4; r++) {
            float v = c[r] + dimf[r] * w64 + bias;
            v = fmaxf(v, 0.f);
            sh1[(q * 4 + r) * 136 + cidx] = f2bf(v);
        }
    }

    // ---- layer 2: 128 -> 64, relu ----
    short8 a2[4];
    #pragma unroll
    for (int s = 0; s < 4; s++)
        a2[s] = *(const short8*)(sh1 + l * 136 + s * 32 + q * 8);

    #pragma unroll
    for (int nt = 0; nt < 4; nt++) {
        f32x4 c = {0.f, 0.f, 0.f, 0.f};
        #pragma unroll
        for (int s = 0; s < 4; s++) {
            short8 b = *(const short8*)(W2b + (nt * 16 + l) * 128 + s * 32 + q * 8);
            c = __builtin_amdgcn_mfma_f32_16x16x32_bf16(a2[s], b, c, 0, 0, 0);
        }
        const int cidx = nt * 16 + l;
        const float bias = b2[cidx];
        #pragma unroll
        for (int r = 0; r < 4; r++) {
            float v = fmaxf(c[r] + bias, 0.f);
            sh2[(q * 4 + r) * 72 + cidx] = f2bf(v);
        }
    }

    // ---- layer 3: 64 -> 256 logits, kept in registers ----
    short8 a3[2];
    #pragma unroll
    for (int s = 0; s < 2; s++)
        a3[s] = *(const short8*)(sh2 + l * 72 + s * 32 + q * 8);

    float lg[16][4];
    #pragma unroll
    for (int nt = 0; nt < 16; nt++) {
        f32x4 c = {0.f, 0.f, 0.f, 0.f};
        #pragma unroll
        for (int s = 0; s < 2; s++) {
            short8 b = *(const short8*)(W3b + (nt * 16 + l) * 64 + s * 32 + q * 8);
            c = __builtin_amdgcn_mfma_f32_16x16x32_bf16(a3[s], b, c, 0, 0, 0);
        }
        const float bias = b3[nt * 16 + l];
        #pragma unroll
        for (int r = 0; r < 4; r++) lg[nt][r] = c[r] + bias;
    }

    // ---- masked softmax (in-register, quad = one logit row) + stores ----
    float* outP = out;
    float* outM = out + (size_t)B_ROWS * 256;

    #pragma unroll
    for (int r = 0; r < 4; r++) {
        const int sc = scl[r];

        float mx = -3.0e38f;
        #pragma unroll
        for (int nt = 0; nt < 16; nt++) {
            int cc = nt * 16 + l;
            if (cc < sc) mx = fmaxf(mx, lg[nt][r]);
        }
        #pragma unroll
        for (int off = 1; off < 16; off <<= 1)
            mx = fmaxf(mx, __shfl_xor(mx, off, 64));

        float sum = 0.f;
        #pragma unroll
        for (int nt = 0; nt < 16; nt++) {
            int cc = nt * 16 + l;
            float e = (cc < sc) ? __expf(lg[nt][r] - mx) : 0.f;
            lg[nt][r] = e;
            sum += e;
        }
        #pragma unroll
        for (int off = 1; off < 16; off <<= 1)
            sum += __shfl_xor(sum, off, 64);

        const float inv = 1.f / sum;
        const size_t orow = (size_t)(rb + q * 4 + r);
        float* po = outP + orow * 256;
        float* mo = outM + orow * 256;
        #pragma unroll
        for (int nt = 0; nt < 16; nt++) {
            int cc = nt * 16 + l;
            po[cc] = lg[nt][r] * inv;
            mo[cc] = (cc < sc) ? 1.0f : 0.0f;
        }
    }
}

extern "C" void kernel_launch(void* const* d_in, const int* in_sizes, int n_in,
                              void* d_out, int out_size, void* d_ws, size_t ws_size,
                              hipStream_t stream) {
    const float* inp = (const float*)d_in[0];
    const int*   st  = (const int*)  d_in[1];
    const float* W1  = (const float*)d_in[2];
    const float* b1  = (const float*)d_in[3];
    const float* W2  = (const float*)d_in[4];
    const float* b2  = (const float*)d_in[5];
    const float* W3  = (const float*)d_in[6];
    const float* b3  = (const float*)d_in[7];
    float* out = (float*)d_out;
    short* wbf = (short*)d_ws;

    convert_weights<<<128, 256, 0, stream>>>(W1, W2, W3, wbf);
    policy_kernel<<<B_ROWS / 64, 256, 0, stream>>>(inp, st, W1, b1, b2, b3, wbf, out);
}

// Round 2
// 673.808 us; speedup vs baseline: 1.0098x; 1.0098x over previous
//
#include <hip/hip_runtime.h>
#include <hip/hip_bf16.h>

#define B_ROWS 262144
#define IN_DIM 65

typedef short short8 __attribute__((ext_vector_type(8)));
typedef float f32x4 __attribute__((ext_vector_type(4)));

static __device__ __forceinline__ short f2bf(float f) {
    union { float f; unsigned u; } v; v.f = f;
    unsigned r = v.u + 0x7fff + ((v.u >> 16) & 1);   // RNE
    return (short)(r >> 16);
}

// ---------------- weight conversion: fp32 -> bf16 into d_ws ----------------
// layout in ws (shorts): W1' [128][64] @0, W2' [64][128] @8192, W3' [256][64] @16384
__global__ void convert_weights(const float* __restrict__ W1,
                                const float* __restrict__ W2,
                                const float* __restrict__ W3,
                                short* __restrict__ ws) {
    int tid = blockIdx.x * 256 + threadIdx.x;
    if (tid < 8192) {
        int n = tid >> 6, k = tid & 63;
        ws[tid] = f2bf(W1[n * IN_DIM + k]);          // drop col 64 (fp32 fixup)
    } else if (tid < 16384) {
        ws[tid] = f2bf(W2[tid - 8192]);              // 64x128 row-major
    } else if (tid < 32768) {
        ws[tid] = f2bf(W3[tid - 16384]);             // 256x64 row-major
    }
}

// ---------------- main fused kernel ----------------
// block = 256 = 4 independent waves; each wave does 16 rows end-to-end.
// Per-wave LDS slice (4352 B) is reused sequentially: sh1 (L1 out, stride 136)
// -> sh2 (L2 out, stride 72) -> T (prob transpose, 4 x 260 dwords). Per-wave
// DS ops execute in order, so aliasing is safe without barriers.
__global__ __launch_bounds__(256) void policy_kernel(
    const float* __restrict__ inp,        // (B, 65)
    const int*   __restrict__ scale_table,// (16,)
    const float* __restrict__ W1,         // (128, 65) fp32 (col-64 fixup)
    const float* __restrict__ b1,         // (128,)
    const float* __restrict__ b2,         // (64,)
    const float* __restrict__ b3,         // (256,)
    const short* __restrict__ wbf,        // bf16 weights in ws
    float* __restrict__ out)              // probs (B,256) then mask (B,256)
{
    __shared__ __align__(16) char ldsbuf[4][4352];

    const int wave = threadIdx.x >> 6;
    const int lane = threadIdx.x & 63;
    const int l = lane & 15;      // col-of-tile / A-row
    const int q = lane >> 4;      // quad

    const int rb = blockIdx.x * 64 + wave * 16;   // 16-row tile base

    short* sh = (short*)(ldsbuf[wave]);
    float* T  = (float*)(ldsbuf[wave]);

    const short* W1b = wbf;          // 128 x 64
    const short* W2b = wbf + 8192;   // 64 x 128
    const short* W3b = wbf + 16384;  // 256 x 64

    // ---- A1 fragments: A[m=lane&15][k=q*8+j], k in [0,64) ----
    short8 a1[2];
    {
        const float* rowp = inp + (size_t)(rb + l) * IN_DIM;
        #pragma unroll
        for (int s = 0; s < 2; s++)
            #pragma unroll
            for (int j = 0; j < 8; j++)
                a1[s][j] = f2bf(rowp[s * 32 + q * 8 + j]);
    }

    // dim idx + scale per accumulator row (rows q*4+r in C-layout)
    float dimf[4]; int scl[4];
    #pragma unroll
    for (int r = 0; r < 4; r++) {
        dimf[r] = inp[(size_t)(rb + q * 4 + r) * IN_DIM + 64];
        scl[r]  = scale_table[(int)dimf[r]];
    }

    // ---- layer 1: 65 -> 128, relu ----
    #pragma unroll
    for (int nt = 0; nt < 8; nt++) {
        f32x4 c = {0.f, 0.f, 0.f, 0.f};
        #pragma unroll
        for (int s = 0; s < 2; s++) {
            short8 b = *(const short8*)(W1b + (nt * 16 + l) * 64 + s * 32 + q * 8);
            c = __builtin_amdgcn_mfma_f32_16x16x32_bf16(a1[s], b, c, 0, 0, 0);
        }
        const int cidx = nt * 16 + l;
        const float w64  = W1[(size_t)cidx * IN_DIM + 64];
        const float bias = b1[cidx];
        #pragma unroll
        for (int r = 0; r < 4; r++) {
            float v = fmaxf(c[r] + dimf[r] * w64 + bias, 0.f);
            sh[(q * 4 + r) * 136 + cidx] = f2bf(v);
        }
    }

    // ---- layer 2: 128 -> 64, relu ----
    short8 a2[4];
    #pragma unroll
    for (int s = 0; s < 4; s++)
        a2[s] = *(const short8*)(sh + l * 136 + s * 32 + q * 8);

    #pragma unroll
    for (int nt = 0; nt < 4; nt++) {
        f32x4 c = {0.f, 0.f, 0.f, 0.f};
        #pragma unroll
        for (int s = 0; s < 4; s++) {
            short8 b = *(const short8*)(W2b + (nt * 16 + l) * 128 + s * 32 + q * 8);
            c = __builtin_amdgcn_mfma_f32_16x16x32_bf16(a2[s], b, c, 0, 0, 0);
        }
        const int cidx = nt * 16 + l;
        const float bias = b2[cidx];
        #pragma unroll
        for (int r = 0; r < 4; r++) {
            float v = fmaxf(c[r] + bias, 0.f);
            sh[(q * 4 + r) * 72 + cidx] = f2bf(v);
        }
    }

    // ---- layer 3: 64 -> 256 logits in registers ----
    short8 a3[2];
    #pragma unroll
    for (int s = 0; s < 2; s++)
        a3[s] = *(const short8*)(sh + l * 72 + s * 32 + q * 8);

    float lg[16][4];
    #pragma unroll
    for (int nt = 0; nt < 16; nt++) {
        f32x4 c = {0.f, 0.f, 0.f, 0.f};
        #pragma unroll
        for (int s = 0; s < 2; s++) {
            short8 b = *(const short8*)(W3b + (nt * 16 + l) * 64 + s * 32 + q * 8);
            c = __builtin_amdgcn_mfma_f32_16x16x32_bf16(a3[s], b, c, 0, 0, 0);
        }
        const float bias = b3[nt * 16 + l];
        #pragma unroll
        for (int r = 0; r < 4; r++) lg[nt][r] = c[r] + bias;
    }

    // ---- masked softmax + LDS transpose + vectorized nontemporal stores ----
    float* outP = out;
    float* outM = out + (size_t)B_ROWS * 256;

    #pragma unroll
    for (int r = 0; r < 4; r++) {
        const int sc = scl[r];

        float mx = -3.0e38f;
        #pragma unroll
        for (int nt = 0; nt < 16; nt++) {
            int cc = nt * 16 + l;
            if (cc < sc) mx = fmaxf(mx, lg[nt][r]);
        }
        #pragma unroll
        for (int off = 1; off < 16; off <<= 1)     // reduce across the 16-lane row group
            mx = fmaxf(mx, __shfl_xor(mx, off, 64));

        float sum = 0.f;
        #pragma unroll
        for (int nt = 0; nt < 16; nt++) {
            int cc = nt * 16 + l;
            float e = (cc < sc) ? __expf(lg[nt][r] - mx) : 0.f;
            lg[nt][r] = e;
            sum += e;
        }
        #pragma unroll
        for (int off = 1; off < 16; off <<= 1)
            sum += __shfl_xor(sum, off, 64);

        const float inv = 1.f / sum;

        // transpose: lane (q,l) owns row q*4+r; write its 16 cols (stride-16)
        #pragma unroll
        for (int nt = 0; nt < 16; nt++)
            T[q * 260 + nt * 16 + l] = lg[nt][r] * inv;

        const size_t orow = (size_t)(rb + q * 4 + r);
        float* po = outP + orow * 256;
        float* mo = outM + orow * 256;
        #pragma unroll
        for (int k = 0; k < 4; k++) {
            const int c0 = k * 64 + l * 4;                 // 16 lanes -> 256B contiguous
            f32x4 v = *(const f32x4*)(T + q * 260 + c0);
            f32x4 m;
            m[0] = (c0 + 0 < sc) ? 1.f : 0.f;
            m[1] = (c0 + 1 < sc) ? 1.f : 0.f;
            m[2] = (c0 + 2 < sc) ? 1.f : 0.f;
            m[3] = (c0 + 3 < sc) ? 1.f : 0.f;
            __builtin_nontemporal_store(v, (f32x4*)(po + c0));
            __builtin_nontemporal_store(m, (f32x4*)(mo + c0));
        }
    }
}

extern "C" void kernel_launch(void* const* d_in, const int* in_sizes, int n_in,
                              void* d_out, int out_size, void* d_ws, size_t ws_size,
                              hipStream_t stream) {
    const float* inp = (const float*)d_in[0];
    const int*   st  = (const int*)  d_in[1];
    const float* W1  = (const float*)d_in[2];
    const float* b1  = (const float*)d_in[3];
    const float* W2  = (const float*)d_in[4];
    const float* b2  = (const float*)d_in[5];
    const float* W3  = (const float*)d_in[6];
    const float* b3  = (const float*)d_in[7];
    float* out = (float*)d_out;
    short* wbf = (short*)d_ws;

    convert_weights<<<128, 256, 0, stream>>>(W1, W2, W3, wbf);
    policy_kernel<<<B_ROWS / 64, 256, 0, stream>>>(inp, st, W1, b1, b2, b3, wbf, out);
}

// Round 3
// 668.464 us; speedup vs baseline: 1.0179x; 1.0080x over previous
//
#include <hip/hip_runtime.h>
#include <hip/hip_bf16.h>

#define B_ROWS 262144
#define IN_DIM 65

typedef short short8 __attribute__((ext_vector_type(8)));
typedef float f32x4 __attribute__((ext_vector_type(4)));

static __device__ __forceinline__ short f2bf(float f) {
    union { float f; unsigned u; } v; v.f = f;
    unsigned r = v.u + 0x7fff + ((v.u >> 16) & 1);   // RNE
    return (short)(r >> 16);
}
static __device__ __forceinline__ float bfbits2f(unsigned hi16) {
    union { unsigned u; float f; } v; v.u = hi16;    // hi16 already in [31:16]
    return v.f;
}

// ---------------- weight conversion: fp32 -> bf16 into d_ws ----------------
// layout in ws (shorts): W1' [128][64] @0, W2' [64][128] @8192, W3' [256][64] @16384
__global__ void convert_weights(const float* __restrict__ W1,
                                const float* __restrict__ W2,
                                const float* __restrict__ W3,
                                short* __restrict__ ws) {
    int tid = blockIdx.x * 256 + threadIdx.x;
    if (tid < 8192) {
        int n = tid >> 6, k = tid & 63;
        ws[tid] = f2bf(W1[n * IN_DIM + k]);          // drop col 64 (fp32 fixup)
    } else if (tid < 16384) {
        ws[tid] = f2bf(W2[tid - 8192]);              // 64x128 row-major
    } else if (tid < 32768) {
        ws[tid] = f2bf(W3[tid - 16384]);             // 256x64 row-major
    }
}

// ---------------- main fused kernel ----------------
// block = 256 = 4 independent waves; each wave does 16 rows end-to-end.
// __launch_bounds__(256,4): cap VGPR at 128 -> 16 waves/CU. Logits held as
// packed bf16 pairs to fit. Per-wave LDS slice (4352 B) reused sequentially:
// sh1 (stride 136) -> sh2 (stride 72) -> T (4 x 260 dwords); per-wave DS
// ordering makes the aliasing safe.
__global__ __launch_bounds__(256, 4) void policy_kernel(
    const float* __restrict__ inp,        // (B, 65)
    const int*   __restrict__ scale_table,// (16,)
    const float* __restrict__ W1,         // (128, 65) fp32 (col-64 fixup)
    const float* __restrict__ b1,         // (128,)
    const float* __restrict__ b2,         // (64,)
    const float* __restrict__ b3,         // (256,)
    const short* __restrict__ wbf,        // bf16 weights in ws
    float* __restrict__ out)              // probs (B,256) then mask (B,256)
{
    __shared__ __align__(16) char ldsbuf[4][4352];

    const int wave = threadIdx.x >> 6;
    const int lane = threadIdx.x & 63;
    const int l = lane & 15;      // col-of-tile / A-row
    const int q = lane >> 4;      // quad

    const int rb = blockIdx.x * 64 + wave * 16;   // 16-row tile base

    short* sh = (short*)(ldsbuf[wave]);
    float* T  = (float*)(ldsbuf[wave]);

    const short* W1b = wbf;          // 128 x 64
    const short* W2b = wbf + 8192;   // 64 x 128
    const short* W3b = wbf + 16384;  // 256 x 64

    // ---- A1 fragments: A[m=lane&15][k=q*8+j], k in [0,64) ----
    short8 a1[2];
    {
        const float* rowp = inp + (size_t)(rb + l) * IN_DIM;
        #pragma unroll
        for (int s = 0; s < 2; s++)
            #pragma unroll
            for (int j = 0; j < 8; j++)
                a1[s][j] = f2bf(rowp[s * 32 + q * 8 + j]);
    }

    // dim idx + scale per accumulator row (rows q*4+r in C-layout)
    float dimf[4]; int scl[4];
    #pragma unroll
    for (int r = 0; r < 4; r++) {
        dimf[r] = inp[(size_t)(rb + q * 4 + r) * IN_DIM + 64];
        scl[r]  = scale_table[(int)dimf[r]];
    }

    // ---- layer 1: 65 -> 128, relu ----
    #pragma unroll
    for (int nt = 0; nt < 8; nt++) {
        f32x4 c = {0.f, 0.f, 0.f, 0.f};
        #pragma unroll
        for (int s = 0; s < 2; s++) {
            short8 b = *(const short8*)(W1b + (nt * 16 + l) * 64 + s * 32 + q * 8);
            c = __builtin_amdgcn_mfma_f32_16x16x32_bf16(a1[s], b, c, 0, 0, 0);
        }
        const int cidx = nt * 16 + l;
        const float w64  = W1[(size_t)cidx * IN_DIM + 64];
        const float bias = b1[cidx];
        #pragma unroll
        for (int r = 0; r < 4; r++) {
            float v = fmaxf(c[r] + dimf[r] * w64 + bias, 0.f);
            sh[(q * 4 + r) * 136 + cidx] = f2bf(v);
        }
    }

    // ---- layer 2: 128 -> 64, relu ----
    short8 a2[4];
    #pragma unroll
    for (int s = 0; s < 4; s++)
        a2[s] = *(const short8*)(sh + l * 136 + s * 32 + q * 8);

    #pragma unroll
    for (int nt = 0; nt < 4; nt++) {
        f32x4 c = {0.f, 0.f, 0.f, 0.f};
        #pragma unroll
        for (int s = 0; s < 4; s++) {
            short8 b = *(const short8*)(W2b + (nt * 16 + l) * 128 + s * 32 + q * 8);
            c = __builtin_amdgcn_mfma_f32_16x16x32_bf16(a2[s], b, c, 0, 0, 0);
        }
        const int cidx = nt * 16 + l;
        const float bias = b2[cidx];
        #pragma unroll
        for (int r = 0; r < 4; r++) {
            float v = fmaxf(c[r] + bias, 0.f);
            sh[(q * 4 + r) * 72 + cidx] = f2bf(v);
        }
    }

    // ---- layer 3: 64 -> 256 logits, packed bf16 (saves 32 VGPRs) ----
    short8 a3[2];
    #pragma unroll
    for (int s = 0; s < 2; s++)
        a3[s] = *(const short8*)(sh + l * 72 + s * 32 + q * 8);

    unsigned lgp[16][2];                  // [nt][pair]: rows (0,1) and (2,3) packed
    #pragma unroll
    for (int nt = 0; nt < 16; nt++) {
        f32x4 c = {0.f, 0.f, 0.f, 0.f};
        #pragma unroll
        for (int s = 0; s < 2; s++) {
            short8 b = *(const short8*)(W3b + (nt * 16 + l) * 64 + s * 32 + q * 8);
            c = __builtin_amdgcn_mfma_f32_16x16x32_bf16(a3[s], b, c, 0, 0, 0);
        }
        const float bias = b3[nt * 16 + l];
        #pragma unroll
        for (int p = 0; p < 2; p++) {
            unsigned lo = (unsigned)(unsigned short)f2bf(c[p * 2 + 0] + bias);
            unsigned hi = (unsigned)(unsigned short)f2bf(c[p * 2 + 1] + bias);
            lgp[nt][p] = lo | (hi << 16);
        }
    }

    // ---- masked softmax + LDS transpose + vectorized nontemporal stores ----
    float* outP = out;
    float* outM = out + (size_t)B_ROWS * 256;

    #pragma unroll
    for (int r = 0; r < 4; r++) {
        const int sc = scl[r];

        float mx = -3.0e38f;
        #pragma unroll
        for (int nt = 0; nt < 16; nt++) {
            unsigned p = lgp[nt][r >> 1];
            float v = bfbits2f((r & 1) ? (p & 0xffff0000u) : (p << 16));
            int cc = nt * 16 + l;
            if (cc < sc) mx = fmaxf(mx, v);
        }
        #pragma unroll
        for (int off = 1; off < 16; off <<= 1)
            mx = fmaxf(mx, __shfl_xor(mx, off, 64));

        // exp -> write unnormalized e straight to T (overlaps the sum chain)
        float sum = 0.f;
        #pragma unroll
        for (int nt = 0; nt < 16; nt++) {
            unsigned p = lgp[nt][r >> 1];
            float v = bfbits2f((r & 1) ? (p & 0xffff0000u) : (p << 16));
            int cc = nt * 16 + l;
            float e = (cc < sc) ? __expf(v - mx) : 0.f;
            T[q * 260 + nt * 16 + l] = e;
            sum += e;
        }
        #pragma unroll
        for (int off = 1; off < 16; off <<= 1)
            sum += __shfl_xor(sum, off, 64);

        const float inv = 1.f / sum;
        const size_t orow = (size_t)(rb + q * 4 + r);
        float* po = outP + orow * 256;
        float* mo = outM + orow * 256;
        #pragma unroll
        for (int k = 0; k < 4; k++) {
            const int c0 = k * 64 + l * 4;                 // 16 lanes -> 256B contiguous
            f32x4 v = *(const f32x4*)(T + q * 260 + c0);
            v[0] *= inv; v[1] *= inv; v[2] *= inv; v[3] *= inv;
            f32x4 m;
            m[0] = (c0 + 0 < sc) ? 1.f : 0.f;
            m[1] = (c0 + 1 < sc) ? 1.f : 0.f;
            m[2] = (c0 + 2 < sc) ? 1.f : 0.f;
            m[3] = (c0 + 3 < sc) ? 1.f : 0.f;
            __builtin_nontemporal_store(v, (f32x4*)(po + c0));
            __builtin_nontemporal_store(m, (f32x4*)(mo + c0));
        }
    }
}

extern "C" void kernel_launch(void* const* d_in, const int* in_sizes, int n_in,
                              void* d_out, int out_size, void* d_ws, size_t ws_size,
                              hipStream_t stream) {
    const float* inp = (const float*)d_in[0];
    const int*   st  = (const int*)  d_in[1];
    const float* W1  = (const float*)d_in[2];
    const float* b1  = (const float*)d_in[3];
    const float* W2  = (const float*)d_in[4];
    const float* b2  = (const float*)d_in[5];
    const float* W3  = (const float*)d_in[6];
    const float* b3  = (const float*)d_in[7];
    float* out = (float*)d_out;
    short* wbf = (short*)d_ws;

    convert_weights<<<128, 256, 0, stream>>>(W1, W2, W3, wbf);
    policy_kernel<<<B_ROWS / 64, 256, 0, stream>>>(inp, st, W1, b1, b2, b3, wbf, out);
}